// Round 9
// baseline (136.234 us; speedup 1.0000x reference)
//
#include <hip/hip_runtime.h>

// T=4096, B=8, E=512. Dual EMA (pos/neg split) along T. fp32 in/out.
//   pb = sigmoid(raw_pos_beta[e]); nb = sigmoid(raw_neg_beta[e])
//   mem_p[t] = pb*mem_p[t-1] + max(x,0)*(1-pb)
//   mem_n[t] = nb*mem_n[t-1] + min(x,0)*(1-nb)
//   out[t,b,e] = mem_p + mem_n
//
// TWO dispatches, ZERO inter-block sync. r6 structure (129.7us champion,
// CHUNK=32) with k_main at HALF-CHUNK granularity: 262144 threads = 16
// waves/CU (2x r6) to cover the scan-chain bubbles in the mixed
// LLC-read + HBM-write stream (r8 proved fold traffic is NOT the
// bottleneck: 4x reduction -> no change; occupancy is the live suspect —
// kernels run ~2x slower than the 6.3TB/s fills, at only 8 waves/CU).
//   k_agg : thread (c,q) scans its 32-t chunk (zero init), writes the
//           full-chunk aggregate agg[c] AND the first-half (16-t)
//           aggregate aggH[c] (snapshot at k=15). 8 MB ws, fully
//           overwritten every launch -> poison-safe.
//   k_main: thread (c,h,q): REDUNDANT fold over agg[j<c] (A=beta^32,
//           L2-resident; traffic 2x r6 = 536MB, known-hidden), compose
//           aggH[c] if h==1 (carry' = beta^16*carry + aggH), then stream
//           16 t-steps x->out (x LLC-resident from k_agg).
// History: r0 trio 135.9 | r1 coop 417 | r5 flags 517 | r6 fold@32 129.7
// | r7 stripe 139.1 | r8 fold@64 132.4. Measured: in-window harness
// overhead (2x268MB poison fills + launch) ~85-95us of every dur_us.
// Fallback: verified r0 trio if ws < 8 MB.

#define T_DIM 4096
#define B_DIM 8
#define E_DIM 512
#define CHUNK_L 32
#define HALF_L 16
#define NCHUNK (T_DIM / CHUNK_L)   // 128
#define BE (B_DIM * E_DIM)         // 4096

__device__ __forceinline__ float sigmoidf_(float x) { return 1.0f / (1.0f + __expf(-x)); }
// beta^32 = five squarings
__device__ __forceinline__ float pow32_(float b) {
    float t = b * b; t *= t; t *= t; t *= t; t *= t; return t;
}
// beta^16 = four squarings
__device__ __forceinline__ float pow16_(float b) {
    float t = b * b; t *= t; t *= t; t *= t; return t;
}

// k_agg: 131072 threads; thread = (c, q). 32 strided float4 loads of x.
// Writes full-chunk agg + first-half aggH.
__global__ __launch_bounds__(256) void k_agg(
        const float* __restrict__ x,
        const float* __restrict__ rp,
        const float* __restrict__ rn,
        float* __restrict__ agg,
        float* __restrict__ aggH) {
    const int gtid = blockIdx.x * 256 + threadIdx.x;
    const int q = gtid & 1023;          // col-quad 0..1023
    const int c = gtid >> 10;           // chunk 0..127
    const int e = (q & 127) * 4;
    const int b = q >> 7;
    const int col = b * E_DIM + e;

    float4 rp4 = *(const float4*)(rp + e);
    float4 rn4 = *(const float4*)(rn + e);
    float bp[4] = {sigmoidf_(rp4.x), sigmoidf_(rp4.y), sigmoidf_(rp4.z), sigmoidf_(rp4.w)};
    float bn[4] = {sigmoidf_(rn4.x), sigmoidf_(rn4.y), sigmoidf_(rn4.z), sigmoidf_(rn4.w)};

    float fp[4] = {0.f, 0.f, 0.f, 0.f};
    float fn[4] = {0.f, 0.f, 0.f, 0.f};
    float hp[4], hn[4];
    const size_t xbase = (size_t)c * CHUNK_L * BE + col;
    #pragma unroll
    for (int k = 0; k < CHUNK_L; k++) {
        float4 xv = *(const float4*)(x + xbase + (size_t)k * BE);
        float f[4] = {xv.x, xv.y, xv.z, xv.w};
        #pragma unroll
        for (int j = 0; j < 4; j++) {
            fp[j] = bp[j] * fp[j] + fmaxf(f[j], 0.f) * (1.0f - bp[j]);
            fn[j] = bn[j] * fn[j] + fminf(f[j], 0.f) * (1.0f - bn[j]);
        }
        if (k == HALF_L - 1) {
            #pragma unroll
            for (int j = 0; j < 4; j++) { hp[j] = fp[j]; hn[j] = fn[j]; }
        }
    }
    *(float4*)(agg  + (size_t)(c * 2 + 0) * BE + col) = make_float4(fp[0], fp[1], fp[2], fp[3]);
    *(float4*)(agg  + (size_t)(c * 2 + 1) * BE + col) = make_float4(fn[0], fn[1], fn[2], fn[3]);
    *(float4*)(aggH + (size_t)(c * 2 + 0) * BE + col) = make_float4(hp[0], hp[1], hp[2], hp[3]);
    *(float4*)(aggH + (size_t)(c * 2 + 1) * BE + col) = make_float4(hn[0], hn[1], hn[2], hn[3]);
}

// k_main: 262144 threads; thread = (c, h, q). Fold, compose half, stream 16.
__global__ __launch_bounds__(256) void ParallelDLIEMA_17789754541002_kernel(
        const float* __restrict__ x,
        const float* __restrict__ rp,
        const float* __restrict__ rn,
        const float* __restrict__ agg,
        const float* __restrict__ aggH,
        float* __restrict__ out) {
    const int gtid = blockIdx.x * 256 + threadIdx.x;
    const int q  = gtid & 1023;         // col-quad 0..1023
    const int ch = gtid >> 10;          // 0..255
    const int h  = ch & 1;              // half 0/1
    const int c  = ch >> 1;             // chunk 0..127
    const int e = (q & 127) * 4;
    const int b = q >> 7;
    const int col = b * E_DIM + e;

    float4 rp4 = *(const float4*)(rp + e);
    float4 rn4 = *(const float4*)(rn + e);
    float bp[4] = {sigmoidf_(rp4.x), sigmoidf_(rp4.y), sigmoidf_(rp4.z), sigmoidf_(rp4.w)};
    float bn[4] = {sigmoidf_(rn4.x), sigmoidf_(rn4.y), sigmoidf_(rn4.z), sigmoidf_(rn4.w)};

    float Ap[4], An[4];                 // beta^32
    #pragma unroll
    for (int j = 0; j < 4; j++) { Ap[j] = pow32_(bp[j]); An[j] = pow32_(bn[j]); }

    // redundant fold: carry into chunk c (ascending j; s = A*s + F_j)
    float sp[4] = {0.f, 0.f, 0.f, 0.f};
    float sn[4] = {0.f, 0.f, 0.f, 0.f};
    #pragma unroll 4
    for (int j = 0; j < c; ++j) {
        float4 ap = *(const float4*)(agg + (size_t)(j * 2 + 0) * BE + col);
        float4 an = *(const float4*)(agg + (size_t)(j * 2 + 1) * BE + col);
        sp[0] = Ap[0] * sp[0] + ap.x;  sn[0] = An[0] * sn[0] + an.x;
        sp[1] = Ap[1] * sp[1] + ap.y;  sn[1] = An[1] * sn[1] + an.y;
        sp[2] = Ap[2] * sp[2] + ap.z;  sn[2] = An[2] * sn[2] + an.z;
        sp[3] = Ap[3] * sp[3] + ap.w;  sn[3] = An[3] * sn[3] + an.w;
    }

    // half-1 threads advance the carry across the first half of their chunk
    if (h) {
        float4 hp = *(const float4*)(aggH + (size_t)(c * 2 + 0) * BE + col);
        float4 hn = *(const float4*)(aggH + (size_t)(c * 2 + 1) * BE + col);
        float hpv[4] = {hp.x, hp.y, hp.z, hp.w};
        float hnv[4] = {hn.x, hn.y, hn.z, hn.w};
        #pragma unroll
        for (int j = 0; j < 4; j++) {
            sp[j] = pow16_(bp[j]) * sp[j] + hpv[j];
            sn[j] = pow16_(bn[j]) * sn[j] + hnv[j];
        }
    }

    // stream 16 t-steps: x (LLC-resident) -> out, seeded with the carry
    const size_t xbase = ((size_t)c * CHUNK_L + (size_t)h * HALF_L) * BE + col;
    #pragma unroll
    for (int k = 0; k < HALF_L; k++) {
        float4 xv = *(const float4*)(x + xbase + (size_t)k * BE);
        float f[4] = {xv.x, xv.y, xv.z, xv.w};
        float o[4];
        #pragma unroll
        for (int j = 0; j < 4; j++) {
            sp[j] = bp[j] * sp[j] + fmaxf(f[j], 0.f) * (1.0f - bp[j]);
            sn[j] = bn[j] * sn[j] + fminf(f[j], 0.f) * (1.0f - bn[j]);
            o[j] = sp[j] + sn[j];
        }
        *(float4*)(out + xbase + (size_t)k * BE) = make_float4(o[0], o[1], o[2], o[3]);
    }
}

// ================= fallback: verified round-0 3-kernel path (135.9us) ====

#define FB_CHUNK_L 16
#define FB_NCHUNK (T_DIM / FB_CHUNK_L)   // 256

__global__ __launch_bounds__(256) void k1_local(
        const float* __restrict__ x, const float* __restrict__ rp,
        const float* __restrict__ rn, float* __restrict__ out) {
    int gtid = blockIdx.x * 256 + threadIdx.x;
    int e4 = gtid & 127; int b = (gtid >> 7) & 7; int c = gtid >> 10; int e = e4 * 4;
    float4 rp4 = *(const float4*)(rp + e);
    float4 rn4 = *(const float4*)(rn + e);
    float bp[4] = {sigmoidf_(rp4.x), sigmoidf_(rp4.y), sigmoidf_(rp4.z), sigmoidf_(rp4.w)};
    float bn[4] = {sigmoidf_(rn4.x), sigmoidf_(rn4.y), sigmoidf_(rn4.z), sigmoidf_(rn4.w)};
    float fp4[4] = {0.f,0.f,0.f,0.f}, fn4[4] = {0.f,0.f,0.f,0.f};
    int base = c * FB_CHUNK_L * BE + b * E_DIM + e;
    #pragma unroll
    for (int k = 0; k < FB_CHUNK_L; k++) {
        float4 xv = *(const float4*)(x + base + k * BE);
        float f[4] = {xv.x, xv.y, xv.z, xv.w};
        #pragma unroll
        for (int j = 0; j < 4; j++) {
            fp4[j] = bp[j] * fp4[j] + fmaxf(f[j], 0.f) * (1.0f - bp[j]);
            fn4[j] = bn[j] * fn4[j] + fminf(f[j], 0.f) * (1.0f - bn[j]);
        }
    }
    *(float4*)(out + base + 0 * BE) = make_float4(fp4[0], fp4[1], fp4[2], fp4[3]);
    *(float4*)(out + base + 1 * BE) = make_float4(fn4[0], fn4[1], fn4[2], fn4[3]);
}

__global__ __launch_bounds__(256) void k_carry(const float* __restrict__ rp,
                                               const float* __restrict__ rn,
                                               float* __restrict__ out) {
    int gtid = blockIdx.x * 256 + threadIdx.x;
    int e = gtid & 511; int b = (gtid >> 9) & 7; int s = gtid >> 12;
    float beta = sigmoidf_(s ? rn[e] : rp[e]);
    float bl = beta * beta; bl = bl * bl; bl = bl * bl; bl = bl * bl;
    float* p = out + s * BE + b * E_DIM + e;
    float carry = 0.f;
    for (int g = 0; g < FB_NCHUNK / 16; g++) {
        float fv[16];
        #pragma unroll
        for (int u = 0; u < 16; u++) fv[u] = p[(g * 16 + u) * (FB_CHUNK_L * BE)];
        #pragma unroll
        for (int u = 0; u < 16; u++) {
            p[(g * 16 + u) * (FB_CHUNK_L * BE)] = carry;
            carry = bl * carry + fv[u];
        }
    }
}

__global__ __launch_bounds__(256) void k_out(const float* __restrict__ x,
                                             const float* __restrict__ rp,
                                             const float* __restrict__ rn,
                                             float* __restrict__ out) {
    int gtid = blockIdx.x * 256 + threadIdx.x;
    int e4 = gtid & 127; int b = (gtid >> 7) & 7; int c = gtid >> 10; int e = e4 * 4;
    float4 rp4 = *(const float4*)(rp + e);
    float4 rn4 = *(const float4*)(rn + e);
    float bp[4] = {sigmoidf_(rp4.x), sigmoidf_(rp4.y), sigmoidf_(rp4.z), sigmoidf_(rp4.w)};
    float bn[4] = {sigmoidf_(rn4.x), sigmoidf_(rn4.y), sigmoidf_(rn4.z), sigmoidf_(rn4.w)};
    int base = c * FB_CHUNK_L * BE + b * E_DIM + e;
    float4 cp = *(const float4*)(out + base + 0 * BE);
    float4 cn = *(const float4*)(out + base + 1 * BE);
    float lp[4] = {cp.x, cp.y, cp.z, cp.w};
    float ln[4] = {cn.x, cn.y, cn.z, cn.w};
    #pragma unroll
    for (int k = 0; k < FB_CHUNK_L; k++) {
        float4 xv = *(const float4*)(x + base + k * BE);
        float f[4] = {xv.x, xv.y, xv.z, xv.w};
        float o[4];
        #pragma unroll
        for (int j = 0; j < 4; j++) {
            lp[j] = bp[j] * lp[j] + fmaxf(f[j], 0.f) * (1.0f - bp[j]);
            ln[j] = bn[j] * ln[j] + fminf(f[j], 0.f) * (1.0f - bn[j]);
            o[j] = lp[j] + ln[j];
        }
        *(float4*)(out + base + k * BE) = make_float4(o[0], o[1], o[2], o[3]);
    }
}

extern "C" void kernel_launch(void* const* d_in, const int* in_sizes, int n_in,
                              void* d_out, int out_size, void* d_ws, size_t ws_size,
                              hipStream_t stream) {
    const float* x  = (const float*)d_in[0];
    const float* rp = (const float*)d_in[1];
    const float* rn = (const float*)d_in[2];
    float* out = (float*)d_out;

    const size_t aggN = (size_t)2 * NCHUNK * BE;          // floats per table
    const size_t need = 2 * aggN * sizeof(float);         // agg + aggH, 8 MB
    if (d_ws != nullptr && ws_size >= need) {
        float* agg  = (float*)d_ws;
        float* aggH = agg + aggN;
        // k_agg: 128 chunks * 1024 quads = 131072 threads = 512 blocks
        k_agg<<<512, 256, 0, stream>>>(x, rp, rn, agg, aggH);
        // k_main: 128 chunks * 2 halves * 1024 quads = 262144 threads = 1024 blocks
        ParallelDLIEMA_17789754541002_kernel<<<1024, 256, 0, stream>>>(x, rp, rn, agg, aggH, out);
    } else {
        // verified fallback (135.9 us)
        k1_local<<<1024, 256, 0, stream>>>(x, rp, rn, out);
        k_carry<<<32, 256, 0, stream>>>(rp, rn, out);
        k_out<<<1024, 256, 0, stream>>>(x, rp, rn, out);
    }
}

// Round 10
// 128.228 us; speedup vs baseline: 1.0624x; 1.0624x over previous
//
#include <hip/hip_runtime.h>

// T=4096, B=8, E=512. Dual EMA (pos/neg split) along T. fp32 in/out.
//   pb = sigmoid(raw_pos_beta[e]); nb = sigmoid(raw_neg_beta[e])
//   mem_p[t] = pb*mem_p[t-1] + max(x,0)*(1-pb)
//   mem_n[t] = nb*mem_n[t-1] + min(x,0)*(1-nb)
//   out[t,b,e] = mem_p + mem_n
//
// r6 champion structure (129.7us) + two k_main-only levers:
//   (1) NON-TEMPORAL stores for out: out is never re-read; default stores
//       write-allocate in L2/L3 and evict the x lines k_main re-reads from
//       LLC. nt protects x residency. (First clean isolation of nt.)
//   (2) LPT ordering: c = NCHUNK-1-c_raw so the longest-fold blocks
//       (c=127: 127-step fold) dispatch FIRST and their folds hide under
//       other blocks' streaming instead of sitting on the tail.
// Structure (TWO dispatches, ZERO inter-block sync):
//   k_agg : thread (c,q) scans its 32-t chunk (zero init), writes chunk
//           aggregate to ws (4 MB, fully overwritten -> poison-safe).
//   k_main: thread (c,q) REDUNDANTLY folds carry over agg[0..c-1]
//           (A=beta^32, L2-resident; r8 proved fold traffic is off the
//           critical path), then streams its chunk x->out (x LLC-resident).
// History: r0 trio 135.9 | r1 coop 417 | r5 flags 517 | r6 fold@32 129.7 |
// r7 stripe 139.1 | r8 fold@64 132.4 | r9 half-grain 136.2.
// Refuted levers: fold traffic (r8), occupancy (r9), stripe loads (r7),
// device-scope sync (r1/r5). Measured: ~86us of in-window harness poison
// fills + ~5us gaps ride on every dur_us.
// Fallback: verified r0 trio if ws < 4 MB.

#define T_DIM 4096
#define B_DIM 8
#define E_DIM 512
#define CHUNK_L 32
#define NCHUNK (T_DIM / CHUNK_L)   // 128
#define BE (B_DIM * E_DIM)         // 4096

typedef float f4_t __attribute__((ext_vector_type(4)));

__device__ __forceinline__ float sigmoidf_(float x) { return 1.0f / (1.0f + __expf(-x)); }
// beta^32 = five squarings
__device__ __forceinline__ float pow32_(float b) {
    float t = b * b; t *= t; t *= t; t *= t; t *= t; return t;
}

// k_agg: 131072 threads; thread = (c, q). 32 strided float4 loads of x.
__global__ __launch_bounds__(256) void k_agg(
        const float* __restrict__ x,
        const float* __restrict__ rp,
        const float* __restrict__ rn,
        float* __restrict__ agg) {
    const int gtid = blockIdx.x * 256 + threadIdx.x;
    const int q = gtid & 1023;          // col-quad 0..1023
    const int c = gtid >> 10;           // chunk 0..127
    const int e = (q & 127) * 4;
    const int b = q >> 7;
    const int col = b * E_DIM + e;

    float4 rp4 = *(const float4*)(rp + e);
    float4 rn4 = *(const float4*)(rn + e);
    float bp[4] = {sigmoidf_(rp4.x), sigmoidf_(rp4.y), sigmoidf_(rp4.z), sigmoidf_(rp4.w)};
    float bn[4] = {sigmoidf_(rn4.x), sigmoidf_(rn4.y), sigmoidf_(rn4.z), sigmoidf_(rn4.w)};

    float fp[4] = {0.f, 0.f, 0.f, 0.f};
    float fn[4] = {0.f, 0.f, 0.f, 0.f};
    const size_t xbase = (size_t)c * CHUNK_L * BE + col;
    #pragma unroll
    for (int k = 0; k < CHUNK_L; k++) {
        float4 xv = *(const float4*)(x + xbase + (size_t)k * BE);
        float f[4] = {xv.x, xv.y, xv.z, xv.w};
        #pragma unroll
        for (int j = 0; j < 4; j++) {
            fp[j] = bp[j] * fp[j] + fmaxf(f[j], 0.f) * (1.0f - bp[j]);
            fn[j] = bn[j] * fn[j] + fminf(f[j], 0.f) * (1.0f - bn[j]);
        }
    }
    *(float4*)(agg + (size_t)(c * 2 + 0) * BE + col) = make_float4(fp[0], fp[1], fp[2], fp[3]);
    *(float4*)(agg + (size_t)(c * 2 + 1) * BE + col) = make_float4(fn[0], fn[1], fn[2], fn[3]);
}

// k_main: redundant prefix fold (L2-resident agg), then stream chunk.
// LPT: longest-fold chunks first. nt stores: out never pollutes LLC.
__global__ __launch_bounds__(256) void ParallelDLIEMA_17789754541002_kernel(
        const float* __restrict__ x,
        const float* __restrict__ rp,
        const float* __restrict__ rn,
        const float* __restrict__ agg,
        float* __restrict__ out) {
    const int gtid = blockIdx.x * 256 + threadIdx.x;
    const int q = gtid & 1023;
    const int c = NCHUNK - 1 - (gtid >> 10);   // LPT: c=127 in block 0
    const int e = (q & 127) * 4;
    const int b = q >> 7;
    const int col = b * E_DIM + e;

    float4 rp4 = *(const float4*)(rp + e);
    float4 rn4 = *(const float4*)(rn + e);
    float bp[4] = {sigmoidf_(rp4.x), sigmoidf_(rp4.y), sigmoidf_(rp4.z), sigmoidf_(rp4.w)};
    float bn[4] = {sigmoidf_(rn4.x), sigmoidf_(rn4.y), sigmoidf_(rn4.z), sigmoidf_(rn4.w)};

    float Ap[4], An[4];                 // beta^32
    #pragma unroll
    for (int j = 0; j < 4; j++) { Ap[j] = pow32_(bp[j]); An[j] = pow32_(bn[j]); }

    // redundant fold: carry into chunk c (ascending j; s = A*s + F_j)
    float sp[4] = {0.f, 0.f, 0.f, 0.f};
    float sn[4] = {0.f, 0.f, 0.f, 0.f};
    #pragma unroll 4
    for (int j = 0; j < c; ++j) {
        float4 ap = *(const float4*)(agg + (size_t)(j * 2 + 0) * BE + col);
        float4 an = *(const float4*)(agg + (size_t)(j * 2 + 1) * BE + col);
        sp[0] = Ap[0] * sp[0] + ap.x;  sn[0] = An[0] * sn[0] + an.x;
        sp[1] = Ap[1] * sp[1] + ap.y;  sn[1] = An[1] * sn[1] + an.y;
        sp[2] = Ap[2] * sp[2] + ap.z;  sn[2] = An[2] * sn[2] + an.z;
        sp[3] = Ap[3] * sp[3] + ap.w;  sn[3] = An[3] * sn[3] + an.w;
    }

    // stream chunk: x (LLC-resident) -> out (non-temporal)
    const size_t xbase = (size_t)c * CHUNK_L * BE + col;
    #pragma unroll
    for (int k = 0; k < CHUNK_L; k++) {
        float4 xv = *(const float4*)(x + xbase + (size_t)k * BE);
        float f[4] = {xv.x, xv.y, xv.z, xv.w};
        float o[4];
        #pragma unroll
        for (int j = 0; j < 4; j++) {
            sp[j] = bp[j] * sp[j] + fmaxf(f[j], 0.f) * (1.0f - bp[j]);
            sn[j] = bn[j] * sn[j] + fminf(f[j], 0.f) * (1.0f - bn[j]);
            o[j] = sp[j] + sn[j];
        }
        f4_t ov = {o[0], o[1], o[2], o[3]};
        __builtin_nontemporal_store(ov, (f4_t*)(out + xbase + (size_t)k * BE));
    }
}

// ================= fallback: verified round-0 3-kernel path (135.9us) ====

#define FB_CHUNK_L 16
#define FB_NCHUNK (T_DIM / FB_CHUNK_L)   // 256

__global__ __launch_bounds__(256) void k1_local(
        const float* __restrict__ x, const float* __restrict__ rp,
        const float* __restrict__ rn, float* __restrict__ out) {
    int gtid = blockIdx.x * 256 + threadIdx.x;
    int e4 = gtid & 127; int b = (gtid >> 7) & 7; int c = gtid >> 10; int e = e4 * 4;
    float4 rp4 = *(const float4*)(rp + e);
    float4 rn4 = *(const float4*)(rn + e);
    float bp[4] = {sigmoidf_(rp4.x), sigmoidf_(rp4.y), sigmoidf_(rp4.z), sigmoidf_(rp4.w)};
    float bn[4] = {sigmoidf_(rn4.x), sigmoidf_(rn4.y), sigmoidf_(rn4.z), sigmoidf_(rn4.w)};
    float fp4[4] = {0.f,0.f,0.f,0.f}, fn4[4] = {0.f,0.f,0.f,0.f};
    int base = c * FB_CHUNK_L * BE + b * E_DIM + e;
    #pragma unroll
    for (int k = 0; k < FB_CHUNK_L; k++) {
        float4 xv = *(const float4*)(x + base + k * BE);
        float f[4] = {xv.x, xv.y, xv.z, xv.w};
        #pragma unroll
        for (int j = 0; j < 4; j++) {
            fp4[j] = bp[j] * fp4[j] + fmaxf(f[j], 0.f) * (1.0f - bp[j]);
            fn4[j] = bn[j] * fn4[j] + fminf(f[j], 0.f) * (1.0f - bn[j]);
        }
    }
    *(float4*)(out + base + 0 * BE) = make_float4(fp4[0], fp4[1], fp4[2], fp4[3]);
    *(float4*)(out + base + 1 * BE) = make_float4(fn4[0], fn4[1], fn4[2], fn4[3]);
}

__global__ __launch_bounds__(256) void k_carry(const float* __restrict__ rp,
                                               const float* __restrict__ rn,
                                               float* __restrict__ out) {
    int gtid = blockIdx.x * 256 + threadIdx.x;
    int e = gtid & 511; int b = (gtid >> 9) & 7; int s = gtid >> 12;
    float beta = sigmoidf_(s ? rn[e] : rp[e]);
    float bl = beta * beta; bl = bl * bl; bl = bl * bl; bl = bl * bl;
    float* p = out + s * BE + b * E_DIM + e;
    float carry = 0.f;
    for (int g = 0; g < FB_NCHUNK / 16; g++) {
        float fv[16];
        #pragma unroll
        for (int u = 0; u < 16; u++) fv[u] = p[(g * 16 + u) * (FB_CHUNK_L * BE)];
        #pragma unroll
        for (int u = 0; u < 16; u++) {
            p[(g * 16 + u) * (FB_CHUNK_L * BE)] = carry;
            carry = bl * carry + fv[u];
        }
    }
}

__global__ __launch_bounds__(256) void k_out(const float* __restrict__ x,
                                             const float* __restrict__ rp,
                                             const float* __restrict__ rn,
                                             float* __restrict__ out) {
    int gtid = blockIdx.x * 256 + threadIdx.x;
    int e4 = gtid & 127; int b = (gtid >> 7) & 7; int c = gtid >> 10; int e = e4 * 4;
    float4 rp4 = *(const float4*)(rp + e);
    float4 rn4 = *(const float4*)(rn + e);
    float bp[4] = {sigmoidf_(rp4.x), sigmoidf_(rp4.y), sigmoidf_(rp4.z), sigmoidf_(rp4.w)};
    float bn[4] = {sigmoidf_(rn4.x), sigmoidf_(rn4.y), sigmoidf_(rn4.z), sigmoidf_(rn4.w)};
    int base = c * FB_CHUNK_L * BE + b * E_DIM + e;
    float4 cp = *(const float4*)(out + base + 0 * BE);
    float4 cn = *(const float4*)(out + base + 1 * BE);
    float lp[4] = {cp.x, cp.y, cp.z, cp.w};
    float ln[4] = {cn.x, cn.y, cn.z, cn.w};
    #pragma unroll
    for (int k = 0; k < FB_CHUNK_L; k++) {
        float4 xv = *(const float4*)(x + base + k * BE);
        float f[4] = {xv.x, xv.y, xv.z, xv.w};
        float o[4];
        #pragma unroll
        for (int j = 0; j < 4; j++) {
            lp[j] = bp[j] * lp[j] + fmaxf(f[j], 0.f) * (1.0f - bp[j]);
            ln[j] = bn[j] * ln[j] + fminf(f[j], 0.f) * (1.0f - bn[j]);
            o[j] = lp[j] + ln[j];
        }
        *(float4*)(out + base + k * BE) = make_float4(o[0], o[1], o[2], o[3]);
    }
}

extern "C" void kernel_launch(void* const* d_in, const int* in_sizes, int n_in,
                              void* d_out, int out_size, void* d_ws, size_t ws_size,
                              hipStream_t stream) {
    const float* x  = (const float*)d_in[0];
    const float* rp = (const float*)d_in[1];
    const float* rn = (const float*)d_in[2];
    float* out = (float*)d_out;

    const size_t need = (size_t)2 * NCHUNK * BE * sizeof(float);   // 4 MB
    if (d_ws != nullptr && ws_size >= need) {
        float* agg = (float*)d_ws;
        // 128 chunks * 1024 col-quads = 131072 threads = 512 blocks
        k_agg<<<512, 256, 0, stream>>>(x, rp, rn, agg);
        ParallelDLIEMA_17789754541002_kernel<<<512, 256, 0, stream>>>(x, rp, rn, agg, out);
    } else {
        // verified fallback (135.9 us)
        k1_local<<<1024, 256, 0, stream>>>(x, rp, rn, out);
        k_carry<<<32, 256, 0, stream>>>(rp, rn, out);
        k_out<<<1024, 256, 0, stream>>>(x, rp, rn, out);
    }
}